// Round 3
// baseline (319.562 us; speedup 1.0000x reference)
//
#include <hip/hip_runtime.h>
#include <hip/hip_bf16.h>
#include <math.h>

#define B_   4
#define T_   4096
#define DIN_ 1024
#define H_   16
#define D_   64
#define M_   (B_*T_)      // 16384
#define N_   (H_*D_*2)    // 2048
#define K_   DIN_         // 1024
#define C_   64           // scan chunks per (b,h) chain
#define CL_  (T_/C_)      // 64 steps per chunk

typedef unsigned short u16;
typedef __attribute__((ext_vector_type(8))) short short8_t;
typedef __attribute__((ext_vector_type(4))) float float4_t;

__device__ __forceinline__ u16 f2bf(float f) {
  unsigned int x = __float_as_uint(f);
  x += 0x7fffu + ((x >> 16) & 1u);   // round-to-nearest-even (finite inputs)
  return (u16)(x >> 16);
}
__device__ __forceinline__ float bf2f(unsigned int u) {
  return __uint_as_float((u & 0xffffu) << 16);
}

// async global->LDS, 16 B per lane. LDS dest = wave-uniform base + lane*16.
__device__ __forceinline__ void g2l16(const u16* g, u16* l) {
  __builtin_amdgcn_global_load_lds(
      (const __attribute__((address_space(1))) void*)g,
      (__attribute__((address_space(3))) void*)l, 16, 0, 0);
}

// ---------------- cast fp32 -> bf16, 8 elems/thread ----------------
__global__ void cast_f32_to_bf16(const float4* __restrict__ src,
                                 uint4* __restrict__ dst, int n8) {
  int i = blockIdx.x * blockDim.x + threadIdx.x;
  if (i >= n8) return;
  float4 a = src[2*i], b = src[2*i+1];
  uint4 o;
  o.x = (unsigned)f2bf(a.x) | ((unsigned)f2bf(a.y) << 16);
  o.y = (unsigned)f2bf(a.z) | ((unsigned)f2bf(a.w) << 16);
  o.z = (unsigned)f2bf(b.x) | ((unsigned)f2bf(b.y) << 16);
  o.w = (unsigned)f2bf(b.z) | ((unsigned)f2bf(b.w) << 16);
  dst[i] = o;
}

// ---------------- cast + transpose weights: src[K][N] f32 -> dst[N][K] bf16 ----------------
__global__ __launch_bounds__(256)
void cast_transpose_w(const float* __restrict__ src, u16* __restrict__ dst) {
  __shared__ float tile[32][33];
  int kb = blockIdx.x * 32;
  int nb = blockIdx.y * 32;
  int tid = threadIdx.x;
  int r  = tid >> 3;           // 0..31
  int c4 = (tid & 7) * 4;      // 0..28
  float4 v = *(const float4*)&src[(size_t)(kb + r) * N_ + nb + c4];
  tile[r][c4+0] = v.x; tile[r][c4+1] = v.y; tile[r][c4+2] = v.z; tile[r][c4+3] = v.w;
  __syncthreads();
  unsigned lo = (unsigned)f2bf(tile[c4+0][r]) | ((unsigned)f2bf(tile[c4+1][r]) << 16);
  unsigned hi = (unsigned)f2bf(tile[c4+2][r]) | ((unsigned)f2bf(tile[c4+3][r]) << 16);
  uint2 o; o.x = lo; o.y = hi;
  *(uint2*)&dst[(size_t)(nb + r) * K_ + kb + c4] = o;
}

// ---------------- GEMM: C[M,N] = A[M,K] * Bt[N,K]^T, relu, split k/v ----------------
// 128x128 tile, BK=32, 4 waves 2x2, 4x4 MFMA tiles/wave; all staging via global_load_lds
__global__ __launch_bounds__(256)
void gemm_kv(const u16* __restrict__ A, const u16* __restrict__ Bt,
             u16* __restrict__ kbuf, u16* __restrict__ vbuf) {
  __shared__ u16 lA[128][32];   // [m][k], k contiguous (layout forced by global_load_lds)
  __shared__ u16 lB[128][32];   // [n][k], k contiguous
  const int tid  = threadIdx.x;
  const int wave = tid >> 6;
  const int lane = tid & 63;
  const int quad = lane >> 4;
  const int l16  = lane & 15;
  const int bm = blockIdx.x * 128;
  const int bn = blockIdx.y * 128;
  const int wm = (wave >> 1) * 64;
  const int wn = (wave & 1) * 64;

  // staging geometry: lane -> (row = wave*16 + lane/4, kchunk = (lane&3)*8)
  const int r4 = lane >> 2;
  const int c8 = (lane & 3) * 8;
  const u16* ga0 = A  + (size_t)(bm + wave*16 + r4) * K_ + c8;
  const u16* ga1 = ga0 + (size_t)64 * K_;
  const u16* gb0 = Bt + (size_t)(bn + wave*16 + r4) * K_ + c8;
  const u16* gb1 = gb0 + (size_t)64 * K_;
  u16* la0 = &lA[wave*16][0];        // wave-uniform LDS bases
  u16* la1 = &lA[64 + wave*16][0];
  u16* lb0 = &lB[wave*16][0];
  u16* lb1 = &lB[64 + wave*16][0];

  float4_t acc[4][4] = {};

  for (int k0 = 0; k0 < K_; k0 += 32) {
    __syncthreads();                 // prior tile's reads done
    g2l16(ga0 + k0, la0);
    g2l16(ga1 + k0, la1);
    g2l16(gb0 + k0, lb0);
    g2l16(gb1 + k0, lb1);
    __syncthreads();                 // drains vmcnt -> LDS visible

    short8_t af[4], bfr[4];
#pragma unroll
    for (int i = 0; i < 4; ++i)
      af[i] = *(const short8_t*)&lA[wm + i*16 + l16][quad*8];
#pragma unroll
    for (int j = 0; j < 4; ++j)
      bfr[j] = *(const short8_t*)&lB[wn + j*16 + l16][quad*8];
#pragma unroll
    for (int i = 0; i < 4; ++i)
#pragma unroll
      for (int j = 0; j < 4; ++j)
        acc[i][j] = __builtin_amdgcn_mfma_f32_16x16x32_bf16(af[i], bfr[j], acc[i][j], 0, 0, 0);
  }

  // epilogue: relu, de-interleave -> kbuf [b,t,h,d] / vbuf [b,h,t,d]
  // C/D layout: col(n) = lane&15, row(m) = quad*4 + reg
#pragma unroll
  for (int j = 0; j < 4; ++j) {
    int n   = bn + wn + j*16 + l16;
    int h   = n >> 7;
    int rem = n & 127;
    int d   = rem >> 1;
    bool isv = (rem & 1) != 0;
#pragma unroll
    for (int i = 0; i < 4; ++i) {
#pragma unroll
      for (int r = 0; r < 4; ++r) {
        int m = bm + wm + i*16 + quad*4 + r;
        float val = acc[i][j][r];
        val = val > 0.f ? val : 0.f;
        size_t kidx = (size_t)m * (H_*D_) + h * D_ + d;
        size_t vidx = (((size_t)(m >> 12) * H_ + h) * T_ + (m & (T_-1))) * D_ + d;
        u16* dst = isv ? vbuf : kbuf;
        dst[isv ? vidx : kidx] = f2bf(val);
      }
    }
  }
}

// ---------------- s[b,h,t] = sum_d q[h,d]*k[b,t,h,d] ----------------
__global__ void compute_s(const u16* __restrict__ kbuf, const float* __restrict__ q,
                          float* __restrict__ sbuf) {
  int row  = blockIdx.x * 4 + (threadIdx.x >> 6);   // b*T + t
  int lane = threadIdx.x & 63;
  int h    = lane >> 2;
  int d0   = (lane & 3) * 16;
  const u16*  kr = kbuf + (size_t)row * (H_*D_) + h * D_ + d0;
  const float* qr = q + h * D_ + d0;
  uint4 p0 = *(const uint4*)kr;
  uint4 p1 = *(const uint4*)(kr + 8);
  float4 q0 = *(const float4*)qr;
  float4 q1 = *(const float4*)(qr + 4);
  float4 q2 = *(const float4*)(qr + 8);
  float4 q3 = *(const float4*)(qr + 12);
  float sum = 0.f;
  sum += bf2f(p0.x) * q0.x + bf2f(p0.x >> 16) * q0.y;
  sum += bf2f(p0.y) * q0.z + bf2f(p0.y >> 16) * q0.w;
  sum += bf2f(p0.z) * q1.x + bf2f(p0.z >> 16) * q1.y;
  sum += bf2f(p0.w) * q1.z + bf2f(p0.w >> 16) * q1.w;
  sum += bf2f(p1.x) * q2.x + bf2f(p1.x >> 16) * q2.y;
  sum += bf2f(p1.y) * q2.z + bf2f(p1.y >> 16) * q2.w;
  sum += bf2f(p1.z) * q3.x + bf2f(p1.z >> 16) * q3.y;
  sum += bf2f(p1.w) * q3.z + bf2f(p1.w >> 16) * q3.w;
  sum += __shfl_xor(sum, 1);
  sum += __shfl_xor(sum, 2);
  if ((lane & 3) == 0) {
    int b = row >> 12;            // T_ = 4096
    int t = row & (T_ - 1);
    sbuf[(size_t)(b * H_ + h) * T_ + t] = sum;
  }
}

// ---------------- chunked scan pass 1: per-chunk aggregates ----------------
__global__ void scan_pass1(const u16* __restrict__ vbuf, const float* __restrict__ sbuf,
                           float* __restrict__ aggM, float* __restrict__ aggU,
                           float* __restrict__ aggW) {
  int blk = blockIdx.x;            // bh*C + c
  int bh  = blk >> 6;
  int c   = blk & (C_ - 1);
  int d   = threadIdx.x;
  int t0  = c * CL_;
  const float* sp = sbuf + (size_t)bh * T_ + t0;
  const u16*   vp = vbuf + ((size_t)bh * T_ + t0) * D_ + d;
  float m = -INFINITY, u = 0.f, w = 0.f;
#pragma unroll 4
  for (int i = 0; i < CL_; ++i) {
    float s = sp[i];
    float v = bf2f(vp[i * D_]);
    float mn    = fmaxf(m, s);
    float alpha = __expf(m - mn);
    float p     = __expf(s - mn);
    u = u * alpha + p;
    w = w * alpha + p * v;
    m = mn;
  }
  aggW[(size_t)blk * D_ + d] = w;
  if (d == 0) { aggM[blk] = m; aggU[blk] = u; }
}

// ---------------- pass 2: exclusive scan of chunk aggregates ----------------
__global__ void scan_pass2(const float* __restrict__ aggM, const float* __restrict__ aggU,
                           const float* __restrict__ aggW,
                           float* __restrict__ preM, float* __restrict__ preU,
                           float* __restrict__ preW) {
  int bh = blockIdx.x;
  int d  = threadIdx.x;
  float m = -INFINITY, u = 0.f, w = 0.f;
  for (int c = 0; c < C_; ++c) {
    int idx = bh * C_ + c;
    preW[(size_t)idx * D_ + d] = w;
    if (d == 0) { preM[idx] = m; preU[idx] = u; }
    float Mc = aggM[idx];
    float Uc = aggU[idx];
    float Wc = aggW[(size_t)idx * D_ + d];
    float mn = fmaxf(m, Mc);
    float ea = __expf(m - mn);
    float eb = __expf(Mc - mn);
    u = u * ea + Uc * eb;
    w = w * ea + Wc * eb;
    m = mn;
  }
}

// ---------------- pass 3 fused with head-reduction ----------------
// block = (b, chunk c): 16 waves, wave h scans its chunk; h=w/u added into LDS tile;
// block writes out[b][t0..t0+63][:] = sum_h. Eliminates the 128 MB partial round-trip.
__global__ __launch_bounds__(1024)
void scan_pass3_fused(const u16* __restrict__ vbuf, const float* __restrict__ sbuf,
                      const float* __restrict__ preM, const float* __restrict__ preU,
                      const float* __restrict__ preW, float* __restrict__ out) {
  __shared__ float acc[CL_][D_];   // 16 KB
  int bc = blockIdx.x;
  int b  = bc >> 6;
  int c  = bc & (C_ - 1);
  int h  = threadIdx.x >> 6;
  int d  = threadIdx.x & 63;
  int tid = threadIdx.x;
#pragma unroll
  for (int j = 0; j < 4; ++j) ((float*)acc)[tid + 1024*j] = 0.f;
  __syncthreads();
  int bh  = b * H_ + h;
  int blk = bh * C_ + c;
  int t0  = c * CL_;
  const float* sp = sbuf + (size_t)bh * T_ + t0;
  const u16*   vp = vbuf + ((size_t)bh * T_ + t0) * D_ + d;
  float m = preM[blk], u = preU[blk], w = preW[(size_t)blk * D_ + d];
  for (int i = 0; i < CL_; ++i) {
    float s = sp[i];
    float v = bf2f(vp[i * D_]);
    float mn    = fmaxf(m, s);
    float alpha = __expf(m - mn);
    float p     = __expf(s - mn);
    u = u * alpha + p;
    w = w * alpha + p * v;
    m = mn;
    atomicAdd(&acc[i][d], __fdividef(w, u));
  }
  __syncthreads();
  float* ob = out + ((size_t)b * T_ + t0) * D_;
#pragma unroll
  for (int j = 0; j < 4; ++j) ob[tid + 1024*j] = ((float*)acc)[tid + 1024*j];
}

extern "C" void kernel_launch(void* const* d_in, const int* in_sizes, int n_in,
                              void* d_out, int out_size, void* d_ws, size_t ws_size,
                              hipStream_t stream) {
  const float* inputs = (const float*)d_in[0];   // (B,T,DIN)
  const float* kvk    = (const float*)d_in[1];   // (DIN,H,D,2)
  const float* qk     = (const float*)d_in[2];   // (H,D)
  float* out = (float*)d_out;
  char* ws = (char*)d_ws;

  u16*   aB   = (u16*)ws;                       // 33,554,432 B  inputs bf16 [M][K]
  u16*   wBt  = (u16*)(ws + 33554432);          //  4,194,304 B  weights bf16 [N][K] (transposed)
  u16*   kb   = (u16*)(ws + 37748736);          // 33,554,432 B  k bf16 [b,t,h,d]
  u16*   vb   = (u16*)(ws + 71303168);          // 33,554,432 B  v bf16 [b,h,t,d]
  float* sb   = (float*)(ws + 104857600);       //  1,048,576 B  s [b,h,t]
  float* aggM = (float*)(ws + 105906176);       //     16,384 B
  float* aggU = (float*)(ws + 105922560);       //     16,384 B
  float* aggW = (float*)(ws + 105938944);       //  1,048,576 B
  float* preM = (float*)(ws + 106987520);       //     16,384 B
  float* preU = (float*)(ws + 107003904);       //     16,384 B
  float* preW = (float*)(ws + 107020288);       //  1,048,576 B  (ends ~108 MB)

  cast_f32_to_bf16<<<8192, 256, 0, stream>>>((const float4*)inputs, (uint4*)aB, M_*K_/8);
  cast_transpose_w<<<dim3(K_/32, N_/32), 256, 0, stream>>>(kvk, wBt);
  gemm_kv<<<dim3(M_/128, N_/128), 256, 0, stream>>>(aB, wBt, kb, vb);
  compute_s<<<M_/4, 256, 0, stream>>>(kb, qk, sb);
  scan_pass1<<<B_*H_*C_, 64, 0, stream>>>(vb, sb, aggM, aggU, aggW);
  scan_pass2<<<B_*H_, 64, 0, stream>>>(aggM, aggU, aggW, preM, preU, preW);
  scan_pass3_fused<<<B_*C_, 1024, 0, stream>>>(vb, sb, preM, preU, preW, out);
}

// Round 4
// 249.000 us; speedup vs baseline: 1.2834x; 1.2834x over previous
//
#include <hip/hip_runtime.h>
#include <hip/hip_bf16.h>
#include <math.h>

#define B_   4
#define T_   4096
#define DIN_ 1024
#define H_   16
#define D_   64
#define M_   (B_*T_)      // 16384
#define N_   (H_*D_*2)    // 2048
#define K_   DIN_         // 1024
#define C_   64           // scan chunks per (b,h) chain
#define CL_  (T_/C_)      // 64 steps per chunk

typedef unsigned short u16;
typedef __attribute__((ext_vector_type(8))) short short8_t;
typedef __attribute__((ext_vector_type(4))) float float4_t;

__device__ __forceinline__ u16 f2bf(float f) {
  unsigned int x = __float_as_uint(f);
  x += 0x7fffu + ((x >> 16) & 1u);   // round-to-nearest-even (finite inputs)
  return (u16)(x >> 16);
}
__device__ __forceinline__ float bf2f(unsigned int u) {
  return __uint_as_float((u & 0xffffu) << 16);
}

// async global->LDS, 16 B per lane. LDS dest = wave-uniform base + lane*16.
__device__ __forceinline__ void g2l16(const u16* g, u16* l) {
  __builtin_amdgcn_global_load_lds(
      (const __attribute__((address_space(1))) void*)g,
      (__attribute__((address_space(3))) void*)l, 16, 0, 0);
}

// ---------------- prep: cast inputs + cast-transpose weights, one launch ----------------
// blocks [0,8192): inputs f32->bf16, 8 elems/thread
// blocks [8192,10240): weights [K][N] f32 -> [N][K] bf16 via 32x32 LDS tile
__global__ __launch_bounds__(256)
void prep(const float* __restrict__ inputs, const float* __restrict__ kvk,
          u16* __restrict__ aB, u16* __restrict__ wBt) {
  __shared__ float tile[32][33];
  int bid = blockIdx.x;
  int tid = threadIdx.x;
  if (bid < 8192) {
    int i = bid * 256 + tid;          // over M*K/8
    const float4* src = (const float4*)inputs;
    float4 a = src[2*i], b = src[2*i+1];
    uint4 o;
    o.x = (unsigned)f2bf(a.x) | ((unsigned)f2bf(a.y) << 16);
    o.y = (unsigned)f2bf(a.z) | ((unsigned)f2bf(a.w) << 16);
    o.z = (unsigned)f2bf(b.x) | ((unsigned)f2bf(b.y) << 16);
    o.w = (unsigned)f2bf(b.z) | ((unsigned)f2bf(b.w) << 16);
    ((uint4*)aB)[i] = o;
  } else {
    int b2 = bid - 8192;              // 2048 blocks
    int kb = (b2 & 31) * 32;          // K/32 = 32
    int nb = (b2 >> 5) * 32;          // N/32 = 64
    int r  = tid >> 3;                // 0..31
    int c4 = (tid & 7) * 4;           // 0..28
    float4 v = *(const float4*)&kvk[(size_t)(kb + r) * N_ + nb + c4];
    tile[r][c4+0] = v.x; tile[r][c4+1] = v.y; tile[r][c4+2] = v.z; tile[r][c4+3] = v.w;
    __syncthreads();
    unsigned lo = (unsigned)f2bf(tile[c4+0][r]) | ((unsigned)f2bf(tile[c4+1][r]) << 16);
    unsigned hi = (unsigned)f2bf(tile[c4+2][r]) | ((unsigned)f2bf(tile[c4+3][r]) << 16);
    uint2 o; o.x = lo; o.y = hi;
    *(uint2*)&wBt[(size_t)(nb + r) * K_ + kb + c4] = o;
  }
}

// ---------------- GEMM: C[M,N] = A[M,K] * Bt[N,K]^T, relu, split k/v ----------------
// 128x128 tile, BK=32, 4 waves 2x2, XOR-swizzled LDS (chunk c of row R at c^((R>>1)&3))
__global__ __launch_bounds__(256)
void gemm_kv(const u16* __restrict__ A, const u16* __restrict__ Bt,
             u16* __restrict__ kbuf, u16* __restrict__ vbuf) {
  __shared__ u16 lA[128][32];
  __shared__ u16 lB[128][32];
  const int tid  = threadIdx.x;
  const int wave = tid >> 6;
  const int lane = tid & 63;
  const int quad = lane >> 4;
  const int l16  = lane & 15;
  const int bm = blockIdx.x * 128;
  const int bn = blockIdx.y * 128;
  const int wm = (wave >> 1) * 64;
  const int wn = (wave & 1) * 64;

  // staging: lane -> (row = wave*16 + r4, k-chunk swizzled by row bits 1-2)
  const int r4 = lane >> 2;
  const int cc = lane & 3;
  const int gk = ((cc ^ ((r4 >> 1) & 3))) * 8;    // swizzled global k-offset
  const u16* ga0 = A  + (size_t)(bm + wave*16 + r4) * K_ + gk;
  const u16* ga1 = ga0 + (size_t)64 * K_;
  const u16* gb0 = Bt + (size_t)(bn + wave*16 + r4) * K_ + gk;
  const u16* gb1 = gb0 + (size_t)64 * K_;
  u16* la0 = &lA[wave*16][0];
  u16* la1 = &lA[64 + wave*16][0];
  u16* lb0 = &lB[wave*16][0];
  u16* lb1 = &lB[64 + wave*16][0];

  // fragment read offset: chunk quad of row R lives at quad ^ ((l16>>1)&3)
  const int swz = (quad ^ ((l16 >> 1) & 3)) * 8;

  float4_t acc[4][4] = {};

  for (int k0 = 0; k0 < K_; k0 += 32) {
    __syncthreads();
    g2l16(ga0 + k0, la0);
    g2l16(ga1 + k0, la1);
    g2l16(gb0 + k0, lb0);
    g2l16(gb1 + k0, lb1);
    __syncthreads();

    short8_t af[4], bfr[4];
#pragma unroll
    for (int i = 0; i < 4; ++i)
      af[i] = *(const short8_t*)&lA[wm + i*16 + l16][swz];
#pragma unroll
    for (int j = 0; j < 4; ++j)
      bfr[j] = *(const short8_t*)&lB[wn + j*16 + l16][swz];
#pragma unroll
    for (int i = 0; i < 4; ++i)
#pragma unroll
      for (int j = 0; j < 4; ++j)
        acc[i][j] = __builtin_amdgcn_mfma_f32_16x16x32_bf16(af[i], bfr[j], acc[i][j], 0, 0, 0);
  }

  // epilogue: relu, de-interleave -> kbuf [b,t,h,d] / vbuf [b,h,t,d]
#pragma unroll
  for (int j = 0; j < 4; ++j) {
    int n   = bn + wn + j*16 + l16;
    int h   = n >> 7;
    int rem = n & 127;
    int d   = rem >> 1;
    bool isv = (rem & 1) != 0;
#pragma unroll
    for (int i = 0; i < 4; ++i) {
#pragma unroll
      for (int r = 0; r < 4; ++r) {
        int m = bm + wm + i*16 + quad*4 + r;
        float val = acc[i][j][r];
        val = val > 0.f ? val : 0.f;
        size_t kidx = (size_t)m * (H_*D_) + h * D_ + d;
        size_t vidx = (((size_t)(m >> 12) * H_ + h) * T_ + (m & (T_-1))) * D_ + d;
        u16* dst = isv ? vbuf : kbuf;
        dst[isv ? vidx : kidx] = f2bf(val);
      }
    }
  }
}

// ---------------- pass 1: inline s-compute + per-chunk aggregates ----------------
// block = (bh, c), 64 threads. Phase A: thread t' dots q[h]·k[b,t0+t',h,:].
// Phase B: thread d scans the chunk.
__global__ __launch_bounds__(64)
void scan_pass1(const u16* __restrict__ kbuf, const u16* __restrict__ vbuf,
                const float* __restrict__ q,
                float* __restrict__ aggM, float* __restrict__ aggU,
                float* __restrict__ aggW) {
  __shared__ float sS[CL_];
  int blk = blockIdx.x;            // bh*C + c
  int bh  = blk >> 6;
  int c   = blk & (C_ - 1);
  int b   = bh >> 4, h = bh & 15;
  int t0  = c * CL_;
  int tid = threadIdx.x;

  const u16*  kr = kbuf + ((size_t)(b * T_ + t0 + tid) * H_ + h) * D_;
  const float* qr = q + h * D_;
  float s = 0.f;
#pragma unroll
  for (int j = 0; j < 8; ++j) {
    uint4 kp = *(const uint4*)(kr + j*8);
    float4 qa = *(const float4*)(qr + j*8);
    float4 qb = *(const float4*)(qr + j*8 + 4);
    s += bf2f(kp.x) * qa.x + bf2f(kp.x >> 16) * qa.y;
    s += bf2f(kp.y) * qa.z + bf2f(kp.y >> 16) * qa.w;
    s += bf2f(kp.z) * qb.x + bf2f(kp.z >> 16) * qb.y;
    s += bf2f(kp.w) * qb.z + bf2f(kp.w >> 16) * qb.w;
  }
  sS[tid] = s;
  __syncthreads();

  int d = tid;
  const u16* vp = vbuf + ((size_t)bh * T_ + t0) * D_ + d;
  float m = -INFINITY, u = 0.f, w = 0.f;
#pragma unroll 4
  for (int i = 0; i < CL_; ++i) {
    float si = sS[i];
    float v  = bf2f(vp[i * D_]);
    float mn    = fmaxf(m, si);
    float alpha = __expf(m - mn);
    float p     = __expf(si - mn);
    u = u * alpha + p;
    w = w * alpha + p * v;
    m = mn;
  }
  aggW[(size_t)blk * D_ + d] = w;
  if (d == 0) { aggM[blk] = m; aggU[blk] = u; }
}

// ---------------- pass 3: prefix (inlined pass2) + scan + h-reduction, no atomics ----
// block = (b, c): 16 waves, wave h owns head h. wbuf slabs + tree-sum every 8 steps.
__global__ __launch_bounds__(1024)
void scan_pass3(const u16* __restrict__ kbuf, const u16* __restrict__ vbuf,
                const float* __restrict__ q,
                const float* __restrict__ aggM, const float* __restrict__ aggU,
                const float* __restrict__ aggW, float* __restrict__ out) {
  __shared__ float sS[H_][CL_];         // 4 KB
  __shared__ float wbuf[H_][8][D_ + 1]; // 33.3 KB, +1 pad breaks reduce-phase conflicts
  int bc = blockIdx.x;
  int b  = bc >> 6;
  int c  = bc & (C_ - 1);
  int tid  = threadIdx.x;
  int h    = tid >> 6;
  int lane = tid & 63;
  int bh   = b * H_ + h;
  int t0   = c * CL_;

  // phase A: s for t = t0+lane (this wave's head)
  const u16*  kr = kbuf + ((size_t)(b * T_ + t0 + lane) * H_ + h) * D_;
  const float* qr = q + h * D_;
  float s = 0.f;
#pragma unroll
  for (int j = 0; j < 8; ++j) {
    uint4 kp = *(const uint4*)(kr + j*8);
    float4 qa = *(const float4*)(qr + j*8);
    float4 qb = *(const float4*)(qr + j*8 + 4);
    s += bf2f(kp.x) * qa.x + bf2f(kp.x >> 16) * qa.y;
    s += bf2f(kp.y) * qa.z + bf2f(kp.y >> 16) * qa.w;
    s += bf2f(kp.z) * qb.x + bf2f(kp.z >> 16) * qb.y;
    s += bf2f(kp.w) * qb.z + bf2f(kp.w >> 16) * qb.w;
  }
  sS[h][lane] = s;

  // phase 0: exclusive prefix over chunks [0,c) of this chain (inlined pass2)
  float m = -INFINITY, u = 0.f, w = 0.f;
  for (int j = 0; j < c; ++j) {
    int idx = bh * C_ + j;
    float Mc = aggM[idx];
    float Uc = aggU[idx];
    float Wc = aggW[(size_t)idx * D_ + lane];
    float mn = fmaxf(m, Mc);
    float ea = __expf(m - mn);
    float eb = __expf(Mc - mn);
    u = u * ea + Uc * eb;
    w = w * ea + Wc * eb;
    m = mn;
  }
  __syncthreads();

  // phase B: seeded scan; every 8 steps tree-reduce over h and store
  const u16* vp = vbuf + ((size_t)bh * T_ + t0) * D_ + lane;
  for (int g = 0; g < 8; ++g) {
#pragma unroll
    for (int ii = 0; ii < 8; ++ii) {
      int i = g * 8 + ii;
      float si = sS[h][i];
      float v  = bf2f(vp[i * D_]);
      float mn    = fmaxf(m, si);
      float alpha = __expf(m - mn);
      float p     = __expf(si - mn);
      u = u * alpha + p;
      w = w * alpha + p * v;
      m = mn;
      wbuf[h][ii][lane] = __fdividef(w, u);
    }
    __syncthreads();
    if (tid < 512) {
      int ii = tid >> 6, dd = tid & 63;
      float acc = 0.f;
#pragma unroll
      for (int hh = 0; hh < H_; ++hh) acc += wbuf[hh][ii][dd];
      out[((size_t)b * T_ + t0 + g*8 + ii) * D_ + dd] = acc;
    }
    __syncthreads();
  }
}

extern "C" void kernel_launch(void* const* d_in, const int* in_sizes, int n_in,
                              void* d_out, int out_size, void* d_ws, size_t ws_size,
                              hipStream_t stream) {
  const float* inputs = (const float*)d_in[0];   // (B,T,DIN)
  const float* kvk    = (const float*)d_in[1];   // (DIN,H,D,2)
  const float* qk     = (const float*)d_in[2];   // (H,D)
  float* out = (float*)d_out;
  char* ws = (char*)d_ws;

  u16*   aB   = (u16*)ws;                       // 33,554,432 B  inputs bf16 [M][K]
  u16*   wBt  = (u16*)(ws + 33554432);          //  4,194,304 B  weights bf16 [N][K]
  u16*   kb   = (u16*)(ws + 37748736);          // 33,554,432 B  k bf16 [b,t,h,d]
  u16*   vb   = (u16*)(ws + 71303168);          // 33,554,432 B  v bf16 [b,h,t,d]
  float* aggM = (float*)(ws + 104857600);       //     16,384 B
  float* aggU = (float*)(ws + 104873984);       //     16,384 B
  float* aggW = (float*)(ws + 104890368);       //  1,048,576 B  (ends ~106 MB)

  prep<<<10240, 256, 0, stream>>>(inputs, kvk, aB, wBt);
  gemm_kv<<<dim3(M_/128, N_/128), 256, 0, stream>>>(aB, wBt, kb, vb);
  scan_pass1<<<B_*H_*C_, 64, 0, stream>>>(kb, vb, qk, aggM, aggU, aggW);
  scan_pass3<<<B_*C_, 1024, 0, stream>>>(kb, vb, qk, aggM, aggU, aggW, out);
}

// Round 5
// 236.926 us; speedup vs baseline: 1.3488x; 1.0510x over previous
//
#include <hip/hip_runtime.h>
#include <hip/hip_bf16.h>
#include <math.h>

#define B_   4
#define T_   4096
#define DIN_ 1024
#define H_   16
#define D_   64
#define M_   (B_*T_)      // 16384
#define N_   (H_*D_*2)    // 2048
#define K_   DIN_         // 1024
#define C_   64           // scan chunks per (b,h) chain
#define CL_  (T_/C_)      // 64 steps per chunk

typedef unsigned short u16;
typedef __attribute__((ext_vector_type(8))) short short8_t;
typedef __attribute__((ext_vector_type(4))) float float4_t;

__device__ __forceinline__ u16 f2bf(float f) {
  unsigned int x = __float_as_uint(f);
  x += 0x7fffu + ((x >> 16) & 1u);   // round-to-nearest-even (finite inputs)
  return (u16)(x >> 16);
}
__device__ __forceinline__ float bf2f(unsigned int u) {
  return __uint_as_float((u & 0xffffu) << 16);
}

// async global->LDS, 16 B per lane. LDS dest = wave-uniform base + lane*16.
__device__ __forceinline__ void g2l16(const u16* g, u16* l) {
  __builtin_amdgcn_global_load_lds(
      (const __attribute__((address_space(1))) void*)g,
      (__attribute__((address_space(3))) void*)l, 16, 0, 0);
}

// ---------------- prep: cast inputs + cast-transpose weights, one launch ----------------
__global__ __launch_bounds__(256)
void prep(const float* __restrict__ inputs, const float* __restrict__ kvk,
          u16* __restrict__ aB, u16* __restrict__ wBt) {
  __shared__ float tile[32][33];
  int bid = blockIdx.x;
  int tid = threadIdx.x;
  if (bid < 8192) {
    int i = bid * 256 + tid;          // over M*K/8
    const float4* src = (const float4*)inputs;
    float4 a = src[2*i], b = src[2*i+1];
    uint4 o;
    o.x = (unsigned)f2bf(a.x) | ((unsigned)f2bf(a.y) << 16);
    o.y = (unsigned)f2bf(a.z) | ((unsigned)f2bf(a.w) << 16);
    o.z = (unsigned)f2bf(b.x) | ((unsigned)f2bf(b.y) << 16);
    o.w = (unsigned)f2bf(b.z) | ((unsigned)f2bf(b.w) << 16);
    ((uint4*)aB)[i] = o;
  } else {
    int b2 = bid - 8192;              // 2048 blocks
    int kb = (b2 & 31) * 32;          // K/32 = 32
    int nb = (b2 >> 5) * 32;          // N/32 = 64
    int r  = tid >> 3;                // 0..31
    int c4 = (tid & 7) * 4;           // 0..28
    float4 v = *(const float4*)&kvk[(size_t)(kb + r) * N_ + nb + c4];
    tile[r][c4+0] = v.x; tile[r][c4+1] = v.y; tile[r][c4+2] = v.z; tile[r][c4+3] = v.w;
    __syncthreads();
    unsigned lo = (unsigned)f2bf(tile[c4+0][r]) | ((unsigned)f2bf(tile[c4+1][r]) << 16);
    unsigned hi = (unsigned)f2bf(tile[c4+2][r]) | ((unsigned)f2bf(tile[c4+3][r]) << 16);
    uint2 o; o.x = lo; o.y = hi;
    *(uint2*)&wBt[(size_t)(nb + r) * K_ + kb + c4] = o;
  }
}

// ---------------- GEMM + fused relu + s-dot + v-transpose-store ----------------
// grid (16, 128): blockIdx.x = head h (n-tile), blockIdx.y = m-tile (one b, 128 t's).
// 128x128 tile, BK=32, 4 waves 2x2, XOR-swizzled LDS. Epilogue computes
// s[b,h,t] in-block (k cols never hit HBM) and stores v via LDS transpose.
__global__ __launch_bounds__(256)
void gemm_kv(const u16* __restrict__ A, const u16* __restrict__ Bt,
             const float* __restrict__ q,
             float* __restrict__ sbuf, u16* __restrict__ vbuf) {
  __shared__ __align__(16) char smem[27136];
  u16*   lA    = (u16*)smem;             // [128][32]  8 KB   (K-loop)
  u16*   lB    = (u16*)(smem + 8192);    // [128][32]  8 KB   (K-loop)
  u16*   vtile = (u16*)smem;             // [128][72] 18432 B (epilogue, reuses lA/lB)
  float* sred  = (float*)(smem + 18432); // [128][17]  8704 B (epilogue)
  __shared__ float qs[D_];

  const int tid  = threadIdx.x;
  const int wave = tid >> 6;
  const int lane = tid & 63;
  const int quad = lane >> 4;
  const int l16  = lane & 15;
  const int h    = blockIdx.x;           // head = n-tile
  const int mt   = blockIdx.y;           // m-tile
  const int bm = mt * 128;
  const int bn = h * 128;
  const int wm = (wave >> 1) * 64;
  const int wn = (wave & 1) * 64;

  if (tid < D_) qs[tid] = q[h * D_ + tid];

  // staging: lane -> (row = wave*16 + r4, k-chunk swizzled by row bits 1-2)
  const int r4 = lane >> 2;
  const int cc = lane & 3;
  const int gk = ((cc ^ ((r4 >> 1) & 3))) * 8;
  const u16* ga0 = A  + (size_t)(bm + wave*16 + r4) * K_ + gk;
  const u16* ga1 = ga0 + (size_t)64 * K_;
  const u16* gb0 = Bt + (size_t)(bn + wave*16 + r4) * K_ + gk;
  const u16* gb1 = gb0 + (size_t)64 * K_;
  u16* la0 = lA + (wave*16) * 32;
  u16* la1 = lA + (64 + wave*16) * 32;
  u16* lb0 = lB + (wave*16) * 32;
  u16* lb1 = lB + (64 + wave*16) * 32;

  // fragment read k-offset: chunk quad of row R lives at quad ^ ((l16>>1)&3)
  const int swz = (quad ^ ((l16 >> 1) & 3)) * 8;

  float4_t acc[4][4] = {};

  for (int k0 = 0; k0 < K_; k0 += 32) {
    __syncthreads();
    g2l16(ga0 + k0, la0);
    g2l16(ga1 + k0, la1);
    g2l16(gb0 + k0, lb0);
    g2l16(gb1 + k0, lb1);
    __syncthreads();

    short8_t af[4], bfr[4];
#pragma unroll
    for (int i = 0; i < 4; ++i)
      af[i] = *(const short8_t*)&lA[(wm + i*16 + l16) * 32 + swz];
#pragma unroll
    for (int j = 0; j < 4; ++j)
      bfr[j] = *(const short8_t*)&lB[(wn + j*16 + l16) * 32 + swz];
#pragma unroll
    for (int i = 0; i < 4; ++i)
#pragma unroll
      for (int j = 0; j < 4; ++j)
        acc[i][j] = __builtin_amdgcn_mfma_f32_16x16x32_bf16(af[i], bfr[j], acc[i][j], 0, 0, 0);
  }

  __syncthreads();   // K-loop LDS reads done; smem now reused as vtile/sred

  // C/D layout: col(n) = l16, row(m) = quad*4 + reg. n parity = l16 parity:
  // even l16 -> k columns (dot with q), odd l16 -> v columns (stage to vtile).
  if (l16 & 1) {
#pragma unroll
    for (int j = 0; j < 4; ++j) {
      int d = ((wn + j*16 + l16) & 127) >> 1;
#pragma unroll
      for (int i = 0; i < 4; ++i)
#pragma unroll
        for (int r = 0; r < 4; ++r) {
          int t = wm + i*16 + quad*4 + r;
          vtile[t*72 + d] = f2bf(fmaxf(acc[i][j][r], 0.f));
        }
    }
  } else {
    int slot = (wn >> 3) + (l16 >> 1);   // 0..15
#pragma unroll
    for (int i = 0; i < 4; ++i)
#pragma unroll
      for (int r = 0; r < 4; ++r) {
        int t = wm + i*16 + quad*4 + r;
        float p = 0.f;
#pragma unroll
        for (int j = 0; j < 4; ++j) {
          int d = ((wn + j*16 + l16) & 127) >> 1;
          p += qs[d] * fmaxf(acc[i][j][r], 0.f);
        }
        sred[t*17 + slot] = p;
      }
  }
  __syncthreads();

  const int b  = mt >> 5;          // 32 m-tiles per batch
  const int t0 = (mt & 31) * 128;

  // coalesced v store: block owns v[b][h][t0:t0+128][:] (contiguous 16 KB)
  {
    int tr = tid >> 3;             // 0..31
    int d0 = (tid & 7) * 8;
    u16* vg = vbuf + ((size_t)(b * H_ + h) * T_ + t0) * D_;
#pragma unroll
    for (int it = 0; it < 4; ++it) {
      int t = tr + 32*it;
      uint4 val = *(const uint4*)&vtile[t*72 + d0];
      *(uint4*)&vg[(size_t)t * D_ + d0] = val;
    }
  }
  // s store: 128 consecutive floats
  if (tid < 128) {
    float ssum = 0.f;
#pragma unroll
    for (int k = 0; k < 16; ++k) ssum += sred[tid*17 + k];
    sbuf[(size_t)(b * H_ + h) * T_ + t0 + tid] = ssum;
  }
}

// ---------------- pass 1: per-chunk aggregates (s from sbuf) ----------------
__global__ __launch_bounds__(64)
void scan_pass1(const u16* __restrict__ vbuf, const float* __restrict__ sbuf,
                float* __restrict__ aggM, float* __restrict__ aggU,
                float* __restrict__ aggW) {
  __shared__ float sS[CL_];
  int blk = blockIdx.x;            // bh*C + c
  int bh  = blk >> 6;
  int c   = blk & (C_ - 1);
  int t0  = c * CL_;
  int tid = threadIdx.x;

  sS[tid] = sbuf[(size_t)bh * T_ + t0 + tid];
  __syncthreads();

  int d = tid;
  const u16* vp = vbuf + ((size_t)bh * T_ + t0) * D_ + d;
  float m = -INFINITY, u = 0.f, w = 0.f;
#pragma unroll 4
  for (int i = 0; i < CL_; ++i) {
    float si = sS[i];
    float v  = bf2f(vp[i * D_]);
    float mn    = fmaxf(m, si);
    float alpha = __expf(m - mn);
    float p     = __expf(si - mn);
    u = u * alpha + p;
    w = w * alpha + p * v;
    m = mn;
  }
  aggW[(size_t)blk * D_ + d] = w;
  if (d == 0) { aggM[blk] = m; aggU[blk] = u; }
}

// ---------------- pass 3: prefix + seeded scan + h-reduction ----------------
__global__ __launch_bounds__(1024)
void scan_pass3(const u16* __restrict__ vbuf, const float* __restrict__ sbuf,
                const float* __restrict__ aggM, const float* __restrict__ aggU,
                const float* __restrict__ aggW, float* __restrict__ out) {
  __shared__ float sS[H_][CL_];         // 4 KB
  __shared__ float wbuf[H_][8][D_ + 1]; // 33.3 KB
  int bc = blockIdx.x;
  int b  = bc >> 6;
  int c  = bc & (C_ - 1);
  int tid  = threadIdx.x;
  int h    = tid >> 6;
  int lane = tid & 63;
  int bh   = b * H_ + h;
  int t0   = c * CL_;

  sS[h][lane] = sbuf[(size_t)bh * T_ + t0 + lane];

  // exclusive prefix over chunks [0,c) of this chain
  float m = -INFINITY, u = 0.f, w = 0.f;
  for (int j = 0; j < c; ++j) {
    int idx = bh * C_ + j;
    float Mc = aggM[idx];
    float Uc = aggU[idx];
    float Wc = aggW[(size_t)idx * D_ + lane];
    float mn = fmaxf(m, Mc);
    float ea = __expf(m - mn);
    float eb = __expf(Mc - mn);
    u = u * ea + Uc * eb;
    w = w * ea + Wc * eb;
    m = mn;
  }
  __syncthreads();

  const u16* vp = vbuf + ((size_t)bh * T_ + t0) * D_ + lane;
  for (int g = 0; g < 8; ++g) {
#pragma unroll
    for (int ii = 0; ii < 8; ++ii) {
      int i = g * 8 + ii;
      float si = sS[h][i];
      float v  = bf2f(vp[i * D_]);
      float mn    = fmaxf(m, si);
      float alpha = __expf(m - mn);
      float p     = __expf(si - mn);
      u = u * alpha + p;
      w = w * alpha + p * v;
      m = mn;
      wbuf[h][ii][lane] = __fdividef(w, u);
    }
    __syncthreads();
    if (tid < 512) {
      int ii = tid >> 6, dd = tid & 63;
      float acc = 0.f;
#pragma unroll
      for (int hh = 0; hh < H_; ++hh) acc += wbuf[hh][ii][dd];
      out[((size_t)b * T_ + t0 + g*8 + ii) * D_ + dd] = acc;
    }
    __syncthreads();
  }
}

extern "C" void kernel_launch(void* const* d_in, const int* in_sizes, int n_in,
                              void* d_out, int out_size, void* d_ws, size_t ws_size,
                              hipStream_t stream) {
  const float* inputs = (const float*)d_in[0];   // (B,T,DIN)
  const float* kvk    = (const float*)d_in[1];   // (DIN,H,D,2)
  const float* qk     = (const float*)d_in[2];   // (H,D)
  float* out = (float*)d_out;
  char* ws = (char*)d_ws;

  u16*   aB   = (u16*)ws;                       // 33,554,432 B  inputs bf16 [M][K]
  u16*   wBt  = (u16*)(ws + 33554432);          //  4,194,304 B  weights bf16 [N][K]
  u16*   vb   = (u16*)(ws + 37748736);          // 33,554,432 B  v bf16 [b,h,t,d]
  float* sb   = (float*)(ws + 71303168);        //  1,048,576 B  s [b,h,t]
  float* aggM = (float*)(ws + 72351744);        //     16,384 B
  float* aggU = (float*)(ws + 72368128);        //     16,384 B
  float* aggW = (float*)(ws + 72384512);        //  1,048,576 B  (ends ~73.4 MB)

  prep<<<10240, 256, 0, stream>>>(inputs, kvk, aB, wBt);
  gemm_kv<<<dim3(H_, M_/128), 256, 0, stream>>>(aB, wBt, qk, sb, vb);
  scan_pass1<<<B_*H_*C_, 64, 0, stream>>>(vb, sb, aggM, aggU, aggW);
  scan_pass3<<<B_*C_, 1024, 0, stream>>>(vb, sb, aggM, aggU, aggW, out);
}